// Round 7
// baseline (796.647 us; speedup 1.0000x reference)
//
#include <hip/hip_runtime.h>
#include <math.h>

#define HH 128
#define WW 128
#define NIMG 4
#define PP 11
#define KSIM 16
#define VRAD 32
#define WINW 65             // 2V+1
#define HREF 40
#define WREF 40
#define NPOS 118            // H-P+1
#define NGROUP (NIMG*HREF*WREF) // 6400
#define EPS_E 30.25f        // n*alpha^2*sigma^2
#define DE_C 151.25f        // D+E
#define INFD 3.0e38f

#define PD2 388             // D2 pitch: 96*4+4
#define DBATCH 96
#define PADW 72             // padded dc-row width (65 -> 72)
#define PADDD (WINW*PADW)   // 4680
#define NBATCH 49           // ceil(4680/96)
#define CNP 120             // cnorm row pitch

// ---------------------------------------------------------------------------
// Stage 0: candidate-patch squared norms (ref-independent, computed once).
// ---------------------------------------------------------------------------
__global__ __launch_bounds__(128)
void bm_norm(const float* __restrict__ y, float* __restrict__ cnorm)
{
    int n = blockIdx.x / NPOS, rr = blockIdx.x % NPOS;
    int cc = threadIdx.x;
    if (cc < NPOS) {
        const float* img = y + n * HH * WW;
        float s = 0.f;
        for (int a = 0; a < PP; a++) {
            const float* rp = &img[(rr + a) * WW + cc];
#pragma unroll
            for (int b = 0; b < PP; b++) s += rp[b] * rp[b];
        }
        cnorm[n * NPOS * CNP + rr * CNP + cc] = s;
    }
}

// ---------------------------------------------------------------------------
// Stage 1: block matching, shared-product tiling, GLOBAL image reads
// (L1-resident working set), LDS = D2 only (31 KB) -> 4 blocks/CU.
// Clamped out-of-range reads only feed candidates masked in phase 2.
// ---------------------------------------------------------------------------
__global__ __launch_bounds__(256, 4)
void bm_kernel(const float* __restrict__ y, const float* __restrict__ cnorm,
               int* __restrict__ inds)
{
    __shared__ float D2[20][PD2];          // 31.0 KB

    const int blk = blockIdx.x;
    const int n  = blk / 100;
    const int tr = blk % 100;
    const int ti = tr / 10, tj = tr % 10;
    const int tid = threadIdx.x;
    const float* img = y + n * HH * WW;
    const float* cn  = cnorm + n * NPOS * CNP;

    const int hr0 = 12 * ti;               // top ref row of tile
    const int wc0 = 12 * tj;               // left ref col of tile

    // selection state: sorted ascending top-16 (static register indexing)
    float sv[16]; int si[16];
#pragma unroll
    for (int q = 0; q < 16; q++) { sv[q] = INFD; si[q] = 0; }

    const int prow1 = tid / 12;            // 0..21 (only <20 used)
    const int dcc   = tid % 12;            // dc-chunk of 8
    const int refq  = tid >> 4;            // phase 2: ref id
    const int dl    = tid & 15;            // d-lane
    const int u = refq >> 2, v = refq & 3;
    const int hr = hr0 + 3 * u, wr = wc0 + 3 * v;

#pragma unroll 1
    for (int b = 0; b < NBATCH; b++) {
        // ---- phase 1: product rows D(x,.) for 96 padded disps ----
        if (tid < 240) {
            int ddp0 = b * DBATCH + dcc * 8;
            if (ddp0 < PADDD) {
                int dr   = ddp0 / PADW - VRAD;
                int dcx0 = ddp0 % PADW;
                int gr1 = hr0 + prow1;                       // always in [0,127]
                int gr2 = min(max(gr1 + dr, 0), HH - 1);     // clamp row
                int gc0 = wc0 - VRAD + dcx0;
                float a1[20], a2[28];
                const float4* r1 = reinterpret_cast<const float4*>(&img[gr1 * WW + wc0]);
#pragma unroll
                for (int q = 0; q < 5; q++) {
                    float4 x4 = r1[q];
                    a1[4*q] = x4.x; a1[4*q+1] = x4.y; a1[4*q+2] = x4.z; a1[4*q+3] = x4.w;
                }
#pragma unroll
                for (int q = 0; q < 7; q++) {
                    int c = min(max(gc0 + 4 * q, 0), WW - 4);  // clamp col chunk
                    float4 x4 = *reinterpret_cast<const float4*>(&img[gr2 * WW + c]);
                    a2[4*q] = x4.x; a2[4*q+1] = x4.y; a2[4*q+2] = x4.z; a2[4*q+3] = x4.w;
                }
#pragma unroll
                for (int k = 0; k < 8; k++) {
                    float d0 = 0.f, d1 = 0.f, d2 = 0.f, d3 = 0.f;
#pragma unroll
                    for (int bb = 0; bb < PP; bb++) {
                        d0 += a1[bb]     * a2[bb + k];
                        d1 += a1[3 + bb] * a2[3 + bb + k];
                        d2 += a1[6 + bb] * a2[6 + bb + k];
                        d3 += a1[9 + bb] * a2[9 + bb + k];
                    }
                    *(float4*)&D2[prow1][(dcc * 8 + k) * 4] = make_float4(d0, d1, d2, d3);
                }
            }
        }
        __syncthreads();
        // ---- phase 2: dists + sorted insertion (6 disps per thread) ----
#pragma unroll
        for (int kk = 0; kk < 6; kk++) {
            int d = dl + 16 * kk;
            int ddp = b * DBATCH + d;
            if (ddp < PADDD) {
                int dcx = ddp % PADW;
                if (dcx < WINW) {
                    int dr = ddp / PADW - VRAD, dc = dcx - VRAD;
                    int rr = hr + dr, cc = wr + dc;
                    if (rr >= 0 && rr <= HH - PP && cc >= 0 && cc <= WW - PP) {
                        float dot = 0.f;
#pragma unroll
                        for (int a = 0; a < PP; a++)
                            dot += D2[3 * u + a][d * 4 + v];
                        float val = cn[rr * CNP + cc] - 2.f * dot;
                        if (dr == 0 && dc == 0) val = -INFD;  // ref always kept
                        if (val < sv[15]) {
                            sv[15] = val; si[15] = ddp;
#pragma unroll
                            for (int q = 15; q > 0; q--) {
                                if (sv[q] < sv[q - 1]) {
                                    float tv = sv[q]; sv[q] = sv[q-1]; sv[q-1] = tv;
                                    int   tq = si[q]; si[q] = si[q-1]; si[q-1] = tq;
                                }
                            }
                        }
                    }
                }
            }
        }
        __syncthreads();
    }

    // ---- merge the 16 per-lane states of each ref (shfl-only) ----
    const int gref = n * (HREF * WREF) + (ti * 4 + u) * WREF + (tj * 4 + v);
#pragma unroll 1
    for (int sel = 0; sel < KSIM; sel++) {
        float bv = sv[0]; int bi = si[0]; int bl = dl;
#pragma unroll
        for (int m = 1; m < 16; m <<= 1) {
            float ov = __shfl_xor(bv, m, 16);
            int   oi = __shfl_xor(bi, m, 16);
            int   ol = __shfl_xor(bl, m, 16);
            if (ov < bv || (ov == bv && ol < bl)) { bv = ov; bi = oi; bl = ol; }
        }
        if (dl == 0) {
            int dr = bi / PADW - VRAD, dc = bi % PADW - VRAD;
            inds[gref * KSIM + sel] = (hr + dr) * NPOS + (wr + dc);
        }
        if (dl == bl) {   // pop head (static shift)
#pragma unroll
            for (int q = 0; q < 15; q++) { sv[q] = sv[q + 1]; si[q] = si[q + 1]; }
            sv[15] = INFD;
        }
    }
}

// ---------------------------------------------------------------------------
// Stage 2+3: tiled denoise, single pass. Patches read from GLOBAL (L1);
// LDS = full acc tile + Qm only (77.6 KB -> 2 blocks/CU). w folded into
// theta; per-thread state ~50 VGPR (no spill).
// ---------------------------------------------------------------------------
__global__ __launch_bounds__(512)
void dn_kernel(const float* __restrict__ y, const int* __restrict__ inds,
               float2* __restrict__ nd, int R)
{
    __shared__ float2 acc[84][85];       // 57.1 KB
    __shared__ float  Qm[16][16][17];    // 17.4 KB (Q -> Qinv -> theta -> A)
    __shared__ float  s1[16][16];
    __shared__ float  s2[16];
    __shared__ float  wl[16][16];
    __shared__ short  pr_[16][16], pc_[16][16];

    const int blk = blockIdx.x;
    const int n  = blk / 100;
    const int tr = blk % 100;
    const int ti = tr / 10, tj = tr % 10;
    const int r0 = 12 * ti - VRAD, c0 = 12 * tj - VRAD;
    const int tid = threadIdx.x;
    const float* img = y + n * HH * WW;

    if (tid < 256) {
        int g = tid >> 4, m = tid & 15;
        int gg = n * (HREF * WREF) + (ti * 4 + (g >> 2)) * WREF + (tj * 4 + (g & 3));
        int idx = inds[gg * KSIM + m];
        pr_[g][m] = (short)(idx / NPOS);
        pc_[g][m] = (short)(idx % NPOS);
    }
    for (int t = tid; t < 84 * 85; t += 512)
        ((float2*)acc)[t] = make_float2(0.f, 0.f);
    __syncthreads();

    // ---- Q: 16 groups x 136 triangle entries, patch reads from global ----
    for (int k = 0; k < 5; k++) {
        int task = tid + k * 512;
        if (task < 16 * 136) {
            int g = task / 136, e = task % 136;
            int i = (int)((sqrtf(8.f * (float)e + 1.f) - 1.f) * 0.5f + 1e-4f);
            int j = e - i * (i + 1) / 2;
            const float* Pi = img + (int)pr_[g][i] * WW + (int)pc_[g][i];
            const float* Pj = img + (int)pr_[g][j] * WW + (int)pc_[g][j];
            float s = (i == j) ? EPS_E : 0.f;
            for (int a = 0; a < PP; a++) {
                const float* Ri = Pi + a * WW;
                const float* Rj = Pj + a * WW;
#pragma unroll
                for (int b = 0; b < PP; b++) s += Ri[b] * Rj[b];
            }
            Qm[g][i][j] = s;
            Qm[g][j][i] = s;
        }
    }
    __syncthreads();

    // ---- lockstep Gauss-Jordan inversion (16 SPD matrices) ----
    const int uu = tid >> 8, ii = (tid >> 4) & 15, jj = tid & 15;
    for (int ks = 0; ks < 16; ks++) {
        float fA[8], rk[8], pv[8], aij[8];
#pragma unroll
        for (int k = 0; k < 8; k++) {
            int g = uu + 2 * k;
            fA[k]  = Qm[g][ii][ks];
            rk[k]  = Qm[g][ks][jj];
            pv[k]  = Qm[g][ks][ks];
            aij[k] = Qm[g][ii][jj];
        }
        __syncthreads();
#pragma unroll
        for (int k = 0; k < 8; k++) {
            int g = uu + 2 * k;
            float inv = 1.f / pv[k];
            float nv;
            if (ii == ks) nv = (jj == ks) ? inv : rk[k] * inv;
            else          nv = (jj == ks) ? -fA[k] * inv : aij[k] - fA[k] * rk[k] * inv;
            Qm[g][ii][jj] = nv;
        }
        __syncthreads();
    }

    // ---- s1, s2, theta (in-place), weights, fold w into theta ----
    if (tid < 256) {
        int g = tid >> 4, a = tid & 15;
        float s = 0.f;
#pragma unroll
        for (int b2 = 0; b2 < 16; b2++) s += Qm[g][a][b2];
        s1[g][a] = s;
    }
    __syncthreads();
    if (tid < 16) {
        float s = 0.f;
#pragma unroll
        for (int a = 0; a < 16; a++) s += s1[tid][a];
        s2[tid] = s;
    }
    __syncthreads();
#pragma unroll
    for (int k = 0; k < 8; k++) {
        int g = uu + 2 * k;
        float t = ((ii == jj) ? 1.f : 0.f)
                - (Qm[g][ii][jj] - s1[g][ii] * s1[g][jj] / s2[g]) * DE_C;
        Qm[g][ii][jj] = t;
    }
    __syncthreads();
    if (tid < 256) {
        int g = tid >> 4, r = tid & 15;
        float s = 0.f;
#pragma unroll
        for (int m2 = 0; m2 < 16; m2++) { float t = Qm[g][m2][r]; s += t * t; }
        s = fminf(fmaxf(s, 1.f / 16.f), 1.f);
        wl[g][r] = 1.f / s;
    }
    __syncthreads();
#pragma unroll
    for (int k = 0; k < 8; k++) {           // A[m][r] = theta[m][r] * w[r]
        int g = uu + 2 * k;
        Qm[g][ii][jj] *= wl[g][jj];
    }
    __syncthreads();

    // ---- xhat + scatter: thread = (g, px), yv[16] only (no spill) ----
    for (int it = 0; it < 4; it++) {
        int task = tid + it * 512;
        if (task < 16 * 121) {
            int g = task / 121, px = task % 121;
            int dra = px / 11, dca = px % 11;
            float yv[16];
#pragma unroll
            for (int m = 0; m < 16; m++)
                yv[m] = img[((int)pr_[g][m] + dra) * WW + (int)pc_[g][m] + dca];
#pragma unroll
            for (int r = 0; r < 16; r++) {
                float xw = 0.f;
#pragma unroll
                for (int m = 0; m < 16; m++)
                    xw += Qm[g][m][r] * yv[m];      // A broadcast read
                float wv = wl[g][r];
                int ar = (int)pr_[g][r] - r0 + dra;
                int ac = (int)pc_[g][r] - c0 + dca;
                float* cell = (float*)&acc[ar][ac];
                __hip_atomic_fetch_add(cell,     xw,
                    __ATOMIC_RELAXED, __HIP_MEMORY_SCOPE_WORKGROUP);
                __hip_atomic_fetch_add(cell + 1, wv,
                    __ATOMIC_RELAXED, __HIP_MEMORY_SCOPE_WORKGROUP);
            }
        }
    }
    __syncthreads();

    // ---- flush tile to global (skip empty cells) ----
    float2* ndI = nd + ((size_t)(blk & (R - 1)) * NIMG + n) * HH * WW;
    for (int t = tid; t < 84 * 84; t += 512) {
        int rr = t / 84, cc = t % 84;
        float2 vv = acc[rr][cc];
        if (vv.y != 0.f) {
            int px = (r0 + rr) * WW + (c0 + cc);
#if defined(__has_builtin) && __has_builtin(__builtin_amdgcn_global_atomic_fadd_v2f32)
            typedef float v2f __attribute__((ext_vector_type(2)));
            __builtin_amdgcn_global_atomic_fadd_v2f32((v2f*)&ndI[px], (v2f){vv.x, vv.y});
#else
            atomicAdd(&ndI[px].x, vv.x);
            atomicAdd(&ndI[px].y, vv.y);
#endif
        }
    }
}

// ---------------------------------------------------------------------------
// Stage 4: out = sum_r num_r / sum_r den_r
// ---------------------------------------------------------------------------
__global__ __launch_bounds__(256)
void fin_kernel(const float2* __restrict__ nd, float* __restrict__ out, int R)
{
    int t = blockIdx.x * 256 + threadIdx.x;
    if (t < NIMG * HH * WW) {
        float sn = 0.f, sd = 0.f;
        for (int r = 0; r < R; r++) {
            float2 vv = nd[(size_t)r * NIMG * HH * WW + t];
            sn += vv.x; sd += vv.y;
        }
        out[t] = sn / sd;
    }
}

extern "C" void kernel_launch(void* const* d_in, const int* in_sizes, int n_in,
                              void* d_out, int out_size, void* d_ws, size_t ws_size,
                              hipStream_t stream)
{
    const float* y = (const float*)d_in[0];
    float* out = (float*)d_out;

    size_t perRep = (size_t)NIMG * HH * WW * sizeof(float2);   // 524288
    size_t indsB  = (size_t)NGROUP * KSIM * sizeof(int);       // 409600
    size_t cnormB = (size_t)NIMG * NPOS * CNP * sizeof(float); // 226560
    int R = 1;
    while (R < 4 && perRep * (size_t)(R * 2) + indsB + cnormB <= ws_size) R <<= 1;

    float2* nd    = (float2*)d_ws;
    int*    inds  = (int*)((char*)d_ws + perRep * (size_t)R);
    float*  cnorm = (float*)((char*)inds + indsB);

    hipMemsetAsync(nd, 0, perRep * (size_t)R, stream);
    bm_norm<<<NIMG * NPOS, 128, 0, stream>>>(y, cnorm);
    bm_kernel<<<NIMG * 100, 256, 0, stream>>>(y, cnorm, inds);
    dn_kernel<<<NIMG * 100, 512, 0, stream>>>(y, inds, nd, R);
    fin_kernel<<<(NIMG * HH * WW + 255) / 256, 256, 0, stream>>>(nd, out, R);
}

// Round 8
// 446.576 us; speedup vs baseline: 1.7839x; 1.7839x over previous
//
#include <hip/hip_runtime.h>
#include <math.h>

#define HH 128
#define WW 128
#define NIMG 4
#define PP 11
#define KSIM 16
#define STRIDE_S 3
#define VRAD 32
#define WINW 65             // 2V+1
#define NTASK (WINW*9)      // 585 tasks: (8-wide dc strip, drx)
#define HREF 40
#define WREF 40
#define NPOS 118            // H-P+1
#define WROWS 75            // 2V+P
#define WPITCH 84           // rows 336B; bank stride 20*drx%32 -> conflict-free
#define NGROUP (NIMG*HREF*WREF) // 6400
#define EPS_E 30.25f        // n*alpha^2*sigma^2
#define DE_C 151.25f        // D+E
#define INFD 3.0e38f
#define RTASK 292           // g2=4, drx=32: the (0,0)-displacement candidate

#define FOOT 84
#define FPITCH 85
#define SPITCH 88

// ---------------------------------------------------------------------------
// Stage 1: block matching (R4 structure; task remap kills bank conflicts).
// dist = |c|^2 - 2<c,r>; colsq from registers; block-wide top-16 selection.
// ---------------------------------------------------------------------------
__global__ __launch_bounds__(256, 5)
void bm_kernel(const float* __restrict__ y, int* __restrict__ inds)
{
    __shared__ float win[WROWS][WPITCH];   // 25.2 KB
    __shared__ float swv[4];
    __shared__ int   swi[4];

    const int blk = blockIdx.x;
    const int n   = blk / (HREF*WREF);
    const int rem = blk % (HREF*WREF);
    const int hr  = (rem / WREF) * STRIDE_S;
    const int wr  = (rem % WREF) * STRIDE_S;
    const float* img = y + n * HH * WW;
    const int tid = threadIdx.x;

    for (int t = tid; t < WROWS * WPITCH; t += 256) {
        int r = t / WPITCH, c = t % WPITCH;
        int gr = hr - VRAD + r, gc = wr - VRAD + c;
        float v = 0.f;
        if (c < WROWS && gr >= 0 && gr < HH && gc >= 0 && gc < WW)
            v = img[gr * WW + gc];
        win[r][c] = v;
    }
    __syncthreads();

    float d[3][8];
#pragma unroll
    for (int s = 0; s < 3; s++)
#pragma unroll
        for (int c = 0; c < 8; c++) d[s][c] = INFD;

#pragma unroll
    for (int s = 0; s < 3; s++) {
        int task = tid + (s << 8);
        if (task < NTASK) {
            // remapped: consecutive lanes -> consecutive drx (same dc-chunk)
            int drx = task % WINW;
            int c0  = (task / WINW) * 8;
            int rr  = hr + drx - VRAD;
            bool rowok = (rr >= 0 && rr <= HH - PP);
            if (rowok) {
                float dot[8];
                float colsq[18];
#pragma unroll
                for (int c = 0; c < 8; c++) dot[c] = 0.f;
#pragma unroll
                for (int j2 = 0; j2 < 18; j2++) colsq[j2] = 0.f;
                for (int a = 0; a < PP; a++) {
                    const float4* w4 = reinterpret_cast<const float4*>(&win[drx + a][c0]);
                    float4 A0 = w4[0], A1 = w4[1], A2 = w4[2], A3 = w4[3];
                    float2 A4 = *reinterpret_cast<const float2*>(&win[drx + a][c0 + 16]);
                    float wv[18] = {A0.x,A0.y,A0.z,A0.w, A1.x,A1.y,A1.z,A1.w,
                                    A2.x,A2.y,A2.z,A2.w, A3.x,A3.y,A3.z,A3.w,
                                    A4.x,A4.y};
                    const float4* r4 = reinterpret_cast<const float4*>(&win[VRAD + a][VRAD]);
                    float4 R0 = r4[0], R1 = r4[1];
                    float2 R2 = *reinterpret_cast<const float2*>(&win[VRAD + a][VRAD + 8]);
                    float  R3 = win[VRAD + a][VRAD + 10];
                    float rv[11] = {R0.x,R0.y,R0.z,R0.w, R1.x,R1.y,R1.z,R1.w,
                                    R2.x,R2.y, R3};
#pragma unroll
                    for (int j2 = 0; j2 < 18; j2++) colsq[j2] += wv[j2] * wv[j2];
#pragma unroll
                    for (int b = 0; b < PP; b++) {
#pragma unroll
                        for (int c = 0; c < 8; c++)
                            dot[c] += wv[b + c] * rv[b];
                    }
                }
#pragma unroll
                for (int j2 = 1; j2 < 18; j2++) colsq[j2] += colsq[j2 - 1];
#pragma unroll
                for (int c = 0; c < 8; c++) {
                    int dcx = c0 + c;
                    int cc  = wr + dcx - VRAD;
                    float norm = colsq[c + 10] - (c ? colsq[c - 1] : 0.f);
                    if (dcx < WINW && cc >= 0 && cc <= WW - PP)
                        d[s][c] = norm - 2.f * dot[c];
                }
            }
            if (task == RTASK) d[s][0] = -INFD;   // reference always kept
        }
    }

    float lval = INFD; int lidx = 0;
#pragma unroll
    for (int s = 0; s < 3; s++)
#pragma unroll
        for (int c = 0; c < 8; c++)
            if (d[s][c] < lval) { lval = d[s][c]; lidx = (s << 3) | c; }

    for (int sel = 0; sel < KSIM; sel++) {
        float rv = lval;
        int   ri = ((tid + ((lidx >> 3) << 8)) << 3) | (lidx & 7);  // task*8+c
#pragma unroll
        for (int off = 32; off > 0; off >>= 1) {
            float ov = __shfl_down(rv, off);
            int   oi = __shfl_down(ri, off);
            if (ov < rv) { rv = ov; ri = oi; }
        }
        if ((tid & 63) == 0) { swv[tid >> 6] = rv; swi[tid >> 6] = ri; }
        __syncthreads();
        float bval = swv[0]; int bidx = swi[0];
#pragma unroll
        for (int w2 = 1; w2 < 4; w2++)
            if (swv[w2] < bval) { bval = swv[w2]; bidx = swi[w2]; }
        if (tid == 0) {
            int task2 = bidx >> 3;
            int drx = task2 % WINW;
            int dcx = (task2 / WINW) * 8 + (bidx & 7);
            inds[blk * KSIM + sel] =
                (hr + drx - VRAD) * NPOS + (wr + dcx - VRAD);
        }
        __syncthreads();
        int otid = (bidx >> 3) & 255;
        if (tid == otid) {
            int code = (((bidx >> 3) >> 8) << 3) | (bidx & 7);
            lval = INFD; lidx = 0;
#pragma unroll
            for (int s = 0; s < 3; s++)
#pragma unroll
                for (int c = 0; c < 8; c++) {
                    if (((s << 3) | c) == code) d[s][c] = INFD;
                    if (d[s][c] < lval) { lval = d[s][c]; lidx = (s << 3) | c; }
                }
        }
    }
}

// ---------------------------------------------------------------------------
// Stage 2+3: tiled denoise. src staged in LDS; half-footprint acc (78.7 KB
// total -> 2 blocks/CU); lean xhat (thread=(g,px), yv[16] only, w folded
// into theta) -> no spills at 128 VGPR.
// ---------------------------------------------------------------------------
__global__ __launch_bounds__(512, 1)
void dn_kernel(const float* __restrict__ y, const int* __restrict__ inds,
               float2* __restrict__ nd, int R)
{
    __shared__ float  src[FOOT][SPITCH];     // 29.6 KB
    __shared__ float2 accH[42][FPITCH];      // 28.6 KB
    __shared__ float  Qm[16][16][17];        // 17.4 KB (Q -> Qinv -> theta -> A)
    __shared__ float  s1[16][16];
    __shared__ float  s2[16];
    __shared__ float  wl[16][16];
    __shared__ short  pr_[16][16], pc_[16][16];

    const int blk = blockIdx.x;
    const int n  = blk / 100;
    const int tr = blk % 100;
    const int ti = tr / 10, tj = tr % 10;
    const int r0 = 12 * ti - VRAD, c0 = 12 * tj - VRAD;
    const int tid = threadIdx.x;
    const float* img = y + n * HH * WW;

    if (tid < 256) {
        int g = tid >> 4, m = tid & 15;
        int gg = n * (HREF * WREF) + (ti * 4 + (g >> 2)) * WREF + (tj * 4 + (g & 3));
        int idx = inds[gg * KSIM + m];
        pr_[g][m] = (short)(idx / NPOS);
        pc_[g][m] = (short)(idx % NPOS);
    }
    for (int t = tid; t < FOOT * FOOT; t += 512) {
        int rr = t / FOOT, cc = t % FOOT;
        int gr = r0 + rr, gc = c0 + cc;
        float vv = 0.f;
        if (gr >= 0 && gr < HH && gc >= 0 && gc < WW) vv = img[gr * WW + gc];
        src[rr][cc] = vv;
    }
    __syncthreads();

    // ---- Q: 16 groups x 136 triangle entries ----
    for (int k = 0; k < 5; k++) {
        int task = tid + k * 512;
        if (task < 16 * 136) {
            int g = task / 136, e = task % 136;
            int i = (int)((sqrtf(8.f * (float)e + 1.f) - 1.f) * 0.5f + 1e-4f);
            int j = e - i * (i + 1) / 2;
            int ari = pr_[g][i] - r0, aci = pc_[g][i] - c0;
            int arj = pr_[g][j] - r0, acj = pc_[g][j] - c0;
            float s = (i == j) ? EPS_E : 0.f;
            for (int a = 0; a < PP; a++) {
                const float* Ri = &src[ari + a][aci];
                const float* Rj = &src[arj + a][acj];
#pragma unroll
                for (int b = 0; b < PP; b++) s += Ri[b] * Rj[b];
            }
            Qm[g][i][j] = s;
            Qm[g][j][i] = s;
        }
    }
    __syncthreads();

    // ---- lockstep Gauss-Jordan inversion (16 SPD matrices) ----
    const int uu = tid >> 8, ii = (tid >> 4) & 15, jj = tid & 15;
    for (int ks = 0; ks < 16; ks++) {
        float fA[8], rk[8], pv[8], aij[8];
#pragma unroll
        for (int k = 0; k < 8; k++) {
            int g = uu + 2 * k;
            fA[k]  = Qm[g][ii][ks];
            rk[k]  = Qm[g][ks][jj];
            pv[k]  = Qm[g][ks][ks];
            aij[k] = Qm[g][ii][jj];
        }
        __syncthreads();
#pragma unroll
        for (int k = 0; k < 8; k++) {
            int g = uu + 2 * k;
            float inv = 1.f / pv[k];
            float nv;
            if (ii == ks) nv = (jj == ks) ? inv : rk[k] * inv;
            else          nv = (jj == ks) ? -fA[k] * inv : aij[k] - fA[k] * rk[k] * inv;
            Qm[g][ii][jj] = nv;
        }
        __syncthreads();
    }

    // ---- s1, s2, theta (in-place), weights, fold w into theta ----
    if (tid < 256) {
        int g = tid >> 4, a = tid & 15;
        float s = 0.f;
#pragma unroll
        for (int b2 = 0; b2 < 16; b2++) s += Qm[g][a][b2];
        s1[g][a] = s;
    }
    __syncthreads();
    if (tid < 16) {
        float s = 0.f;
#pragma unroll
        for (int a = 0; a < 16; a++) s += s1[tid][a];
        s2[tid] = s;
    }
    __syncthreads();
#pragma unroll
    for (int k = 0; k < 8; k++) {
        int g = uu + 2 * k;
        float t = ((ii == jj) ? 1.f : 0.f)
                - (Qm[g][ii][jj] - s1[g][ii] * s1[g][jj] / s2[g]) * DE_C;
        Qm[g][ii][jj] = t;
    }
    __syncthreads();
    if (tid < 256) {
        int g = tid >> 4, r = tid & 15;
        float s = 0.f;
#pragma unroll
        for (int m2 = 0; m2 < 16; m2++) { float t = Qm[g][m2][r]; s += t * t; }
        s = fminf(fmaxf(s, 1.f / 16.f), 1.f);
        wl[g][r] = 1.f / s;
    }
    __syncthreads();
#pragma unroll
    for (int k = 0; k < 8; k++) {            // A[m][r] = theta[m][r] * w[r]
        int g = uu + 2 * k;
        Qm[g][ii][jj] *= wl[g][jj];
    }
    __syncthreads();

    // ---- two half-passes: lean xhat + LDS scatter + flush ----
    float2* ndI = nd + ((size_t)(blk & (R - 1)) * NIMG + n) * HH * WW;
#pragma unroll 1
    for (int half = 0; half < 2; half++) {
        const int h0 = half * 42;
        for (int t = tid; t < 42 * FPITCH; t += 512)
            ((float2*)accH)[t] = make_float2(0.f, 0.f);
        __syncthreads();

        for (int it = 0; it < 4; it++) {
            int task = tid + it * 512;
            if (task < 16 * 121) {
                int g = task / 121, px = task % 121;
                int dra = px / 11, dca = px % 11;
                float yv[16];
#pragma unroll
                for (int m = 0; m < 16; m++)
                    yv[m] = src[(int)pr_[g][m] - r0 + dra][(int)pc_[g][m] - c0 + dca];
#pragma unroll
                for (int r = 0; r < 16; r++) {
                    int ar = (int)pr_[g][r] - r0;
                    int hA = ar + dra;
                    if (hA >= h0 && hA < h0 + 42) {
                        float xw = 0.f;
#pragma unroll
                        for (int m = 0; m < 16; m++)
                            xw += Qm[g][m][r] * yv[m];    // A broadcast read
                        int ac = (int)pc_[g][r] - c0;
                        float* cell = (float*)&accH[hA - h0][ac + dca];
                        __hip_atomic_fetch_add(cell,     xw,
                            __ATOMIC_RELAXED, __HIP_MEMORY_SCOPE_WORKGROUP);
                        __hip_atomic_fetch_add(cell + 1, wl[g][r],
                            __ATOMIC_RELAXED, __HIP_MEMORY_SCOPE_WORKGROUP);
                    }
                }
            }
        }
        __syncthreads();

        for (int t = tid; t < 42 * FOOT; t += 512) {
            int rr = t / FOOT, cc = t % FOOT;
            float2 vv = accH[rr][cc];
            if (vv.y != 0.f) {
                int px = (r0 + h0 + rr) * WW + (c0 + cc);
#if defined(__has_builtin) && __has_builtin(__builtin_amdgcn_global_atomic_fadd_v2f32)
                typedef float v2f __attribute__((ext_vector_type(2)));
                __builtin_amdgcn_global_atomic_fadd_v2f32((v2f*)&ndI[px], (v2f){vv.x, vv.y});
#else
                atomicAdd(&ndI[px].x, vv.x);
                atomicAdd(&ndI[px].y, vv.y);
#endif
            }
        }
        __syncthreads();
    }
}

// ---------------------------------------------------------------------------
// Stage 4: out = sum_r num_r / sum_r den_r
// ---------------------------------------------------------------------------
__global__ __launch_bounds__(256)
void fin_kernel(const float2* __restrict__ nd, float* __restrict__ out, int R)
{
    int t = blockIdx.x * 256 + threadIdx.x;
    if (t < NIMG * HH * WW) {
        float sn = 0.f, sd = 0.f;
        for (int r = 0; r < R; r++) {
            float2 vv = nd[(size_t)r * NIMG * HH * WW + t];
            sn += vv.x; sd += vv.y;
        }
        out[t] = sn / sd;
    }
}

extern "C" void kernel_launch(void* const* d_in, const int* in_sizes, int n_in,
                              void* d_out, int out_size, void* d_ws, size_t ws_size,
                              hipStream_t stream)
{
    const float* y = (const float*)d_in[0];
    float* out = (float*)d_out;

    size_t perRep = (size_t)NIMG * HH * WW * sizeof(float2);   // 524288
    size_t indsB  = (size_t)NGROUP * KSIM * sizeof(int);       // 409600
    int R = 1;
    while (R < 4 && perRep * (size_t)(R * 2) + indsB <= ws_size) R <<= 1;

    float2* nd   = (float2*)d_ws;
    int*    inds = (int*)((char*)d_ws + perRep * (size_t)R);

    hipMemsetAsync(nd, 0, perRep * (size_t)R, stream);
    bm_kernel<<<NGROUP, 256, 0, stream>>>(y, inds);
    dn_kernel<<<NIMG * 100, 512, 0, stream>>>(y, inds, nd, R);
    fin_kernel<<<(NIMG * HH * WW + 255) / 256, 256, 0, stream>>>(nd, out, R);
}